// Round 1
// baseline (888.745 us; speedup 1.0000x reference)
//
#include <hip/hip_runtime.h>
#include <math.h>

__device__ __forceinline__ float2 cmul(float2 a, float2 b) {
    return make_float2(a.x * b.x - a.y * b.y, a.x * b.y + a.y * b.x);
}

// ---------------- conv1 + relu : x[2048,1,28,28] -> h1[2048,32,26,26] ----------------
__global__ __launch_bounds__(256) void conv1_kernel(
    const float* __restrict__ x, const float* __restrict__ w,
    const float* __restrict__ bias, float* __restrict__ h1, int total)
{
    int idx = blockIdx.x * 256 + threadIdx.x;
    if (idx >= total) return;
    int xc = idx % 26;
    int t = idx / 26;
    int yr = t % 26; t /= 26;
    int oc = t % 32;
    int b = t / 32;
    const float* xp = x + b * 784 + yr * 28 + xc;
    const float* wp = w + oc * 9;
    float acc = bias[oc];
#pragma unroll
    for (int ky = 0; ky < 3; ++ky)
#pragma unroll
        for (int kx = 0; kx < 3; ++kx)
            acc = fmaf(xp[ky * 28 + kx], wp[ky * 3 + kx], acc);
    h1[idx] = fmaxf(acc, 0.f);
}

// ------- conv2 + relu + 2x2 maxpool : h1 -> pooled[2048,64,12,12] (fused) -------
// block: 256 thr = 32 oc-pairs x (2 pooled rows x 4 px-tiles of 3)
// grid: 2048 * 6  (b, py0 = 2*(bx%6))
__global__ __launch_bounds__(256) void conv2_kernel(
    const float* __restrict__ h1, const float* __restrict__ w,
    const float* __restrict__ bias, float* __restrict__ pooled)
{
    __shared__ float in_t[32][6][26];
    int bx = blockIdx.x;
    int b = bx / 6;
    int py0 = (bx % 6) * 2;
    int tid = threadIdx.x;
    for (int e = tid; e < 32 * 6 * 26; e += 256) {
        int col = e % 26;
        int t = e / 26;
        int row = t % 6;
        int ic = t / 6;
        in_t[ic][row][col] = h1[((b * 32 + ic) * 26 + (2 * py0 + row)) * 26 + col];
    }
    __syncthreads();
    int ocg = tid >> 3;          // 0..31
    int posg = tid & 7;          // 0..7
    int pyr = posg >> 2;         // 0..1
    int pxt = posg & 3;          // 0..3 -> pooled cols 3*pxt..3*pxt+2
    int oc0 = ocg * 2;
    int colbase = 6 * pxt;       // conv cols colbase..colbase+5, input cols ..+7
    int rowbase = 2 * pyr;       // input rows rowbase..rowbase+3

    float acc[2][2][6];
#pragma unroll
    for (int o = 0; o < 2; ++o)
#pragma unroll
        for (int r = 0; r < 2; ++r)
#pragma unroll
            for (int c = 0; c < 6; ++c) acc[o][r][c] = 0.f;

    for (int ic = 0; ic < 32; ++ic) {
        float wA[9], wB[9];
        const float* wp = w + (oc0 * 32 + ic) * 9;
#pragma unroll
        for (int k = 0; k < 9; ++k) { wA[k] = wp[k]; wB[k] = wp[288 + k]; }
        float patch[4][8];
#pragma unroll
        for (int r = 0; r < 4; ++r)
#pragma unroll
            for (int c = 0; c < 8; c += 2) {
                float2 v = *(const float2*)&in_t[ic][rowbase + r][colbase + c];
                patch[r][c] = v.x; patch[r][c + 1] = v.y;
            }
#pragma unroll
        for (int ky = 0; ky < 3; ++ky)
#pragma unroll
            for (int kx = 0; kx < 3; ++kx) {
                float a0 = wA[ky * 3 + kx], a1 = wB[ky * 3 + kx];
#pragma unroll
                for (int r = 0; r < 2; ++r)
#pragma unroll
                    for (int c = 0; c < 6; ++c) {
                        float pv = patch[r + ky][c + kx];
                        acc[0][r][c] = fmaf(pv, a0, acc[0][r][c]);
                        acc[1][r][c] = fmaf(pv, a1, acc[1][r][c]);
                    }
            }
    }
    int py = py0 + pyr;
#pragma unroll
    for (int o = 0; o < 2; ++o) {
        float bia = bias[oc0 + o];
#pragma unroll
        for (int pc = 0; pc < 3; ++pc) {
            float m = fmaxf(fmaxf(acc[o][0][2 * pc], acc[o][0][2 * pc + 1]),
                            fmaxf(acc[o][1][2 * pc], acc[o][1][2 * pc + 1]));
            pooled[((b * 64 + oc0 + o) * 12 + py) * 12 + (3 * pxt + pc)] =
                fmaxf(m + bia, 0.f);
        }
    }
}

// ---------------- fc1 split-K GEMM: pooled[2048,9216] x w[128,9216]^T ----------------
// grid (32, 8): 64-row M tile, all 128 N, K slice of 1152
__global__ __launch_bounds__(256) void fc1_gemm_kernel(
    const float* __restrict__ xin, const float* __restrict__ w,
    float* __restrict__ part)
{
    __shared__ float Xs[64][33];
    __shared__ float Ws[128][33];
    int mt = blockIdx.x;
    int ks = blockIdx.y;
    int tid = threadIdx.x;
    int bm0 = mt * 64;
    int kbase = ks * 1152;
    int ty = tid >> 4, tx = tid & 15;
    float acc[4][8];
#pragma unroll
    for (int i = 0; i < 4; ++i)
#pragma unroll
        for (int j = 0; j < 8; ++j) acc[i][j] = 0.f;

    for (int kt = 0; kt < 36; ++kt) {
        int k0 = kbase + kt * 32;
#pragma unroll
        for (int i = 0; i < 8; ++i) {
            int e = tid + i * 256;
            Xs[e >> 5][e & 31] = xin[(bm0 + (e >> 5)) * 9216 + k0 + (e & 31)];
        }
#pragma unroll
        for (int i = 0; i < 16; ++i) {
            int e = tid + i * 256;
            Ws[e >> 5][e & 31] = w[(e >> 5) * 9216 + k0 + (e & 31)];
        }
        __syncthreads();
#pragma unroll
        for (int kk = 0; kk < 32; ++kk) {
            float xv[4], wv[8];
#pragma unroll
            for (int i = 0; i < 4; ++i) xv[i] = Xs[ty * 4 + i][kk];
#pragma unroll
            for (int j = 0; j < 8; ++j) wv[j] = Ws[tx * 8 + j][kk];
#pragma unroll
            for (int i = 0; i < 4; ++i)
#pragma unroll
                for (int j = 0; j < 8; ++j)
                    acc[i][j] = fmaf(xv[i], wv[j], acc[i][j]);
        }
        __syncthreads();
    }
    float* pp = part + (size_t)ks * (2048 * 128);
#pragma unroll
    for (int i = 0; i < 4; ++i)
#pragma unroll
        for (int j = 0; j < 8; ++j)
            pp[(bm0 + ty * 4 + i) * 128 + tx * 8 + j] = acc[i][j];
}

__global__ __launch_bounds__(256) void fc1_reduce_kernel(
    const float* __restrict__ part, const float* __restrict__ bias,
    float* __restrict__ outp)
{
    int idx = blockIdx.x * 256 + threadIdx.x;   // < 262144
    float s = 0.f;
#pragma unroll
    for (int ks = 0; ks < 8; ++ks) s += part[ks * 262144 + idx];
    outp[idx] = fmaxf(s + bias[idx & 127], 0.f);
}

// ---------------- fc2 + sigmoid*2pi -> angles[2048,10] ----------------
__global__ __launch_bounds__(256) void fc2_kernel(
    const float* __restrict__ h, const float* __restrict__ w,
    const float* __restrict__ bias, float* __restrict__ ang)
{
    int idx = blockIdx.x * 256 + threadIdx.x;
    if (idx >= 20480) return;
    int b = idx / 10, n = idx % 10;
    const float* hp = h + b * 128;
    const float* wp = w + n * 128;
    float s = bias[n];
    for (int k = 0; k < 128; ++k) s = fmaf(hp[k], wp[k], s);
    ang[idx] = 6.28318530718f / (1.f + expf(-s));
}

// ---------------- quantum circuit + <Y_k> + log_softmax ----------------
__device__ __forceinline__ void apply_rot(float2* s, int p, float phi, float th,
                                          float om, int tid)
{
    float c, sn; sincosf(0.5f * th, &sn, &c);
    float A = 0.5f * (phi + om), Bv = 0.5f * (phi - om);
    float cA, sA; sincosf(A, &sA, &cA);
    float cB, sB; sincosf(Bv, &sB, &cB);
    float2 m00 = make_float2(cA * c, -sA * c);
    float2 m01 = make_float2(-cB * sn, -sB * sn);
    float2 m10 = make_float2(cB * sn, -sB * sn);
    float2 m11 = make_float2(cA * c, sA * c);
    for (int q = tid; q < 512; q += 256) {
        int i0 = ((q >> p) << (p + 1)) | (q & ((1 << p) - 1));
        int i1 = i0 | (1 << p);
        float2 aa = s[i0], bb = s[i1];
        s[i0] = make_float2(m00.x * aa.x - m00.y * aa.y + m01.x * bb.x - m01.y * bb.y,
                            m00.x * aa.y + m00.y * aa.x + m01.x * bb.y + m01.y * bb.x);
        s[i1] = make_float2(m10.x * aa.x - m10.y * aa.y + m11.x * bb.x - m11.y * bb.y,
                            m10.x * aa.y + m10.y * aa.x + m11.x * bb.y + m11.y * bb.x);
    }
}

__global__ __launch_bounds__(256) void quantum_kernel(
    const float* __restrict__ ang, const float* __restrict__ theta0,
    const float* __restrict__ theta_rz, const float* __restrict__ theta_ps,
    const float* __restrict__ rot_p, float* __restrict__ out)
{
    __shared__ float2 s[1024];
    __shared__ float red[40];
    int b = blockIdx.x;
    int tid = threadIdx.x;

    float a[10];
#pragma unroll
    for (int k = 0; k < 10; ++k) a[k] = ang[b * 10 + k];
    float th[10];
#pragma unroll
    for (int k = 0; k < 10; ++k) th[k] = theta0[k] + a[k];
    th[1] += a[1];
    th[5] -= 0.78539816339745f;   // RX(-pi/4) on wire 5

    // per-wire single-qubit prefix states v[k] (wire k -> bit 9-k)
    float2 v[10][2];
#pragma unroll
    for (int k = 0; k < 10; ++k) {
        float c, sn; sincosf(0.5f * th[k], &sn, &c);
        v[k][0] = make_float2(c, 0.f);
        v[k][1] = make_float2(0.f, -sn);
    }
    { // wire2: RY(a2)
        float c, sn; sincosf(0.5f * a[2], &sn, &c);
        float2 v0 = v[2][0], v1 = v[2][1];
        v[2][0] = make_float2(c * v0.x - sn * v1.x, c * v0.y - sn * v1.y);
        v[2][1] = make_float2(sn * v0.x + c * v1.x, sn * v0.y + c * v1.y);
    }
    { // wire3: RZ(a3)
        float c, sn; sincosf(0.5f * a[3], &sn, &c);
        v[3][0] = cmul(v[3][0], make_float2(c, -sn));
        v[3][1] = cmul(v[3][1], make_float2(c, sn));
    }
    { // wire4: S
        float2 t = v[4][1];
        v[4][1] = make_float2(-t.y, t.x);
    }
    { // wire5: T
        const float r = 0.70710678118655f;
        float2 t = v[5][1];
        v[5][1] = make_float2(r * (t.x - t.y), r * (t.x + t.y));
    }
    { // wire6: RZ(theta_rz)
        float c, sn; sincosf(0.5f * theta_rz[0], &sn, &c);
        v[6][0] = cmul(v[6][0], make_float2(c, -sn));
        v[6][1] = cmul(v[6][1], make_float2(c, sn));
    }
    { // wire7: SX
        float2 p = v[7][0], q = v[7][1];
        v[7][0] = make_float2(0.5f * ((p.x - p.y) + (q.x + q.y)),
                              0.5f * ((p.x + p.y) + (q.y - q.x)));
        v[7][1] = make_float2(0.5f * ((p.x + p.y) + (q.x - q.y)),
                              0.5f * ((p.y - p.x) + (q.x + q.y)));
    }

    // init product state
    for (int i = tid; i < 1024; i += 256) {
        float2 c = v[0][(i >> 9) & 1];
#pragma unroll
        for (int k = 1; k < 10; ++k)
            c = cmul(c, v[k][(i >> (9 - k)) & 1]);
        s[i] = c;
    }
    __syncthreads();

    // CZ(0,5): bits 9,4
    for (int i = tid; i < 1024; i += 256)
        if (((i >> 9) & 1) && ((i >> 4) & 1)) { s[i].x = -s[i].x; s[i].y = -s[i].y; }
    __syncthreads();
    { // CNOT(0,5): ctrl bit9, tgt bit4
        int j = tid;
        int i0 = 512 | ((j >> 4) << 5) | (j & 15);
        int i1 = i0 | 16;
        float2 t0 = s[i0], t1 = s[i1];
        s[i0] = t1; s[i1] = t0;
    }
    __syncthreads();
    { // CY(0,5)
        int j = tid;
        int i0 = 512 | ((j >> 4) << 5) | (j & 15);
        int i1 = i0 | 16;
        float2 t0 = s[i0], t1 = s[i1];
        s[i0] = make_float2(t1.y, -t1.x);   // -i * s1
        s[i1] = make_float2(-t0.y, t0.x);   //  i * s0
    }
    __syncthreads();
    { // CY(3,8): ctrl bit6, tgt bit1
        int j = tid;
        int i0 = (j & 1) | (((j >> 1) & 15) << 2) | (((j >> 5) & 7) << 7) | 64;
        int i1 = i0 | 2;
        float2 t0 = s[i0], t1 = s[i1];
        s[i0] = make_float2(t1.y, -t1.x);
        s[i1] = make_float2(-t0.y, t0.x);
    }
    __syncthreads();
    { // SWAP(2,3): bits 7,6
        int j = tid;
        int i0 = (j & 63) | 128 | (((j >> 6) & 3) << 8);
        int i1 = i0 ^ 0xC0;
        float2 t0 = s[i0], t1 = s[i1];
        s[i0] = t1; s[i1] = t0;
    }
    __syncthreads();
    if (tid < 128) { // CSWAP(4,5,6): ctrl bit5, swap bits 4,3
        int j = tid;
        int i0 = (j & 7) | 16 | 32 | (((j >> 3) & 15) << 6);
        int i1 = i0 ^ 0x18;
        float2 t0 = s[i0], t1 = s[i1];
        s[i0] = t1; s[i1] = t0;
    }
    __syncthreads();
    if (tid < 128) { // TOFF(8,5,0): ctrl bits 1,4, tgt bit9
        int j = tid;
        int i0 = (j & 1) | 2 | (((j >> 1) & 3) << 2) | 16 | (((j >> 3) & 15) << 5);
        int i1 = i0 | 512;
        float2 t0 = s[i0], t1 = s[i1];
        s[i0] = t1; s[i1] = t0;
    }
    __syncthreads();
    { // Phase(theta_ps) wire8 (bit1); Phase(a7) wire7 (bit2)
        float c1, s1; sincosf(theta_ps[0], &s1, &c1);
        float c2, s2; sincosf(a[7], &s2, &c2);
        float2 p1 = make_float2(c1, s1), p2 = make_float2(c2, s2);
        for (int i = tid; i < 1024; i += 256) {
            float2 t = s[i];
            if ((i >> 1) & 1) t = cmul(t, p1);
            if ((i >> 2) & 1) t = cmul(t, p2);
            s[i] = t;
        }
    }
    __syncthreads();
    apply_rot(s, 5, rot_p[0], rot_p[1], rot_p[2], tid);   // Rot on wire4 (bit5)
    __syncthreads();
    apply_rot(s, 4, a[6], a[7], a[8], tid);               // Rot on wire5 (bit4)
    __syncthreads();

    // expectations <Y_k> = 2 * sum_pairs Im(conj(s0)*s1)
    int wave = tid >> 6;
    for (int k = 0; k < 10; ++k) {
        int p = 9 - k;
        float part = 0.f;
        for (int q = tid; q < 512; q += 256) {
            int i0 = ((q >> p) << (p + 1)) | (q & ((1 << p) - 1));
            int i1 = i0 | (1 << p);
            float2 aa = s[i0], bb = s[i1];
            part += aa.x * bb.y - aa.y * bb.x;
        }
        part *= 2.f;
#pragma unroll
        for (int off = 32; off > 0; off >>= 1)
            part += __shfl_down(part, off, 64);
        if ((tid & 63) == 0) red[k * 4 + wave] = part;
    }
    __syncthreads();
    if (tid == 0) {
        float ev[10];
        float mx = -1e30f;
#pragma unroll
        for (int k = 0; k < 10; ++k) {
            ev[k] = red[k * 4] + red[k * 4 + 1] + red[k * 4 + 2] + red[k * 4 + 3];
            mx = fmaxf(mx, ev[k]);
        }
        float sum = 0.f;
#pragma unroll
        for (int k = 0; k < 10; ++k) sum += expf(ev[k] - mx);
        float lse = mx + logf(sum);
#pragma unroll
        for (int k = 0; k < 10; ++k) out[b * 10 + k] = ev[k] - lse;
    }
}

extern "C" void kernel_launch(void* const* d_in, const int* in_sizes, int n_in,
                              void* d_out, int out_size, void* d_ws, size_t ws_size,
                              hipStream_t stream)
{
    (void)in_sizes; (void)n_in; (void)out_size; (void)ws_size;
    const float* x    = (const float*)d_in[0];
    const float* c1w  = (const float*)d_in[1];
    const float* c1b  = (const float*)d_in[2];
    const float* c2w  = (const float*)d_in[3];
    const float* c2b  = (const float*)d_in[4];
    const float* f1w  = (const float*)d_in[5];
    const float* f1b  = (const float*)d_in[6];
    const float* f2w  = (const float*)d_in[7];
    const float* f2b  = (const float*)d_in[8];
    const float* th0  = (const float*)d_in[9];
    const float* trz  = (const float*)d_in[10];
    const float* tps  = (const float*)d_in[11];
    const float* rotp = (const float*)d_in[12];
    float* out = (float*)d_out;

    float* h1     = (float*)d_ws;            // 44,302,336 floats [2048,32,26,26]
    float* pooled = h1 + 44302336;           // 18,874,368 floats [2048,9216]
    float* part   = h1;                      // alias: h1 dead after conv2 (8*2048*128)
    float* fc1o   = pooled + 18874368;       // 262,144 floats
    float* ang    = fc1o + 262144;           // 20,480 floats

    int total1 = 2048 * 32 * 26 * 26;
    conv1_kernel<<<(total1 + 255) / 256, 256, 0, stream>>>(x, c1w, c1b, h1, total1);
    conv2_kernel<<<2048 * 6, 256, 0, stream>>>(h1, c2w, c2b, pooled);
    fc1_gemm_kernel<<<dim3(32, 8), 256, 0, stream>>>(pooled, f1w, part);
    fc1_reduce_kernel<<<1024, 256, 0, stream>>>(part, f1b, fc1o);
    fc2_kernel<<<80, 256, 0, stream>>>(fc1o, f2w, f2b, ang);
    quantum_kernel<<<2048, 256, 0, stream>>>(ang, th0, trz, tps, rotp, out);
}

// Round 3
// 216.484 us; speedup vs baseline: 4.1054x; 4.1054x over previous
//
#include <hip/hip_runtime.h>
#include <math.h>

typedef short short8 __attribute__((ext_vector_type(8)));
typedef float f32x4 __attribute__((ext_vector_type(4)));
typedef float f32x16 __attribute__((ext_vector_type(16)));

__device__ __forceinline__ float2 cmul(float2 a, float2 b) {
    return make_float2(a.x * b.x - a.y * b.y, a.x * b.y + a.y * b.x);
}

__device__ __forceinline__ ushort f2bf(float f) {
    uint u = __float_as_uint(f);
    uint r = (u + 0x7FFFu + ((u >> 16) & 1u)) >> 16;
    return (ushort)r;
}

// ---- prep: conv2 weights -> wt2[tap][icg][oc][ic8] bf16 ; fc1 weights -> bf16 ----
__global__ __launch_bounds__(256) void prep_kernel(
    const float* __restrict__ c2w, const float* __restrict__ f1w,
    ushort* __restrict__ wt2, ushort* __restrict__ wf1)
{
    int i = blockIdx.x * 256 + threadIdx.x;
    if (i < 18432) {
        int icl = i & 7;
        int t = i >> 3;
        int oc = t & 63;
        int t2 = t >> 6;
        int icg = t2 & 3;
        int tap = t2 >> 2;
        int ic = icg * 8 + icl;
        wt2[i] = f2bf(c2w[(oc * 32 + ic) * 9 + tap]);
    } else if (i < 18432 + 1179648) {
        int j = i - 18432;
        wf1[j] = f2bf(f1w[j]);
    }
}

// ---- conv1 + relu -> h1b[b][icg][pix][ic8] bf16 (icg = oc>>3) ----
__global__ __launch_bounds__(256) void conv1_kernel(
    const float* __restrict__ x, const float* __restrict__ w1,
    const float* __restrict__ b1, ushort* __restrict__ h1b)
{
    __shared__ float wl[288];
    __shared__ float bl[32];
    int tid = threadIdx.x;
    for (int e = tid; e < 288; e += 256) wl[e] = w1[e];   // FIX: was if(tid<288) under 256 thr
    if (tid < 32) bl[tid] = b1[tid];
    __syncthreads();
    int e = blockIdx.x * 256 + tid;          // 2048*676*4 total, exact grid
    int icg = e & 3;
    int t = e >> 2;
    int pix = t % 676;
    int b = t / 676;
    int y = pix / 26, xc = pix % 26;
    const float* xp = x + b * 784 + y * 28 + xc;
    float in9[9];
#pragma unroll
    for (int ky = 0; ky < 3; ++ky)
#pragma unroll
        for (int kx = 0; kx < 3; ++kx) in9[ky * 3 + kx] = xp[ky * 28 + kx];
    short8 outv;
#pragma unroll
    for (int o = 0; o < 8; ++o) {
        int oc = icg * 8 + o;
        float acc = bl[oc];
#pragma unroll
        for (int k = 0; k < 9; ++k) acc = fmaf(in9[k], wl[oc * 9 + k], acc);
        outv[o] = (short)f2bf(fmaxf(acc, 0.f));
    }
    *(short8*)&h1b[((b * 4 + icg) * 676 + pix) * 8] = outv;
}

// ---- conv2 implicit-GEMM MFMA + bias + relu + 2x2 maxpool -> pooled bf16 [b][9216] ----
// one block per image, 384 thr = 6 waves; 9 taps x GEMM(64oc x 576px x 32ic)
__global__ __launch_bounds__(384) void conv2_mfma(
    const ushort* __restrict__ h1b, const ushort* __restrict__ wt2,
    const float* __restrict__ c2b, ushort* __restrict__ pooled)
{
    __shared__ ushort lds[40064];   // inb [0,21632) ; wlds [21632,40064); conv reuse [0,36864)
    __shared__ float biasl[64];
    int b = blockIdx.x;
    int tid = threadIdx.x;

    const uint4* src = (const uint4*)(h1b + (size_t)b * 21632);
    uint4* ldsv = (uint4*)lds;
    for (int e = tid; e < 2704; e += 384) ldsv[e] = src[e];
    const uint4* wsrc = (const uint4*)wt2;
    uint4* wdst = (uint4*)(lds + 21632);
    for (int e = tid; e < 2304; e += 384) wdst[e] = wsrc[e];
    if (tid < 64) biasl[tid] = c2b[tid];
    __syncthreads();

    int wid = tid >> 6;
    int lane = tid & 63;
    int lo = lane & 31;
    int hi = lane >> 5;

    f32x16 acc[2][3];
#pragma unroll
    for (int mt = 0; mt < 2; ++mt)
#pragma unroll
        for (int i = 0; i < 3; ++i) acc[mt][i] = (f32x16)0.f;

    int pixb[3];
#pragma unroll
    for (int i = 0; i < 3; ++i) {
        int px = (wid * 3 + i) * 32 + lo;
        pixb[i] = (px / 24) * 26 + (px % 24);
    }

#pragma unroll
    for (int tap = 0; tap < 9; ++tap) {
        int ky = tap / 3, kx = tap % 3;
        int toff = (ky * 26 + kx) * 8;
        short8 a[2][2];
#pragma unroll
        for (int mt = 0; mt < 2; ++mt)
#pragma unroll
            for (int ks = 0; ks < 2; ++ks)
                a[mt][ks] = *(const short8*)&lds[21632 +
                    ((tap * 4 + ks * 2 + hi) * 64 + mt * 32 + lo) * 8];
#pragma unroll
        for (int i = 0; i < 3; ++i) {
#pragma unroll
            for (int ks = 0; ks < 2; ++ks) {
                short8 bf = *(const short8*)&lds[((ks * 2 + hi) * 676 + pixb[i]) * 8 + toff];
                acc[0][i] = __builtin_amdgcn_mfma_f32_32x32x16_bf16(a[0][ks], bf, acc[0][i], 0, 0, 0);
                acc[1][i] = __builtin_amdgcn_mfma_f32_32x32x16_bf16(a[1][ks], bf, acc[1][i], 0, 0, 0);
            }
        }
    }
    __syncthreads();

    // conv result (bias+relu, bf16) into LDS [oc][px]
#pragma unroll
    for (int mt = 0; mt < 2; ++mt)
#pragma unroll
        for (int i = 0; i < 3; ++i) {
            int px = (wid * 3 + i) * 32 + lo;
#pragma unroll
            for (int r = 0; r < 16; ++r) {
                int oc = mt * 32 + (r & 3) + 8 * (r >> 2) + 4 * hi;
                float v = acc[mt][i][r] + biasl[oc];
                lds[oc * 576 + px] = f2bf(fmaxf(v, 0.f));
            }
        }
    __syncthreads();

    // 2x2 maxpool (ushort compare valid: relu'd bf16 >= 0)
    for (int e = tid; e < 9216; e += 384) {
        int oc = e / 144;
        int rr = e % 144;
        int py = rr / 12, pxp = rr % 12;
        int base = oc * 576 + py * 48 + pxp * 2;
        ushort m0 = lds[base]     > lds[base + 1]  ? lds[base]      : lds[base + 1];
        ushort m1 = lds[base + 24] > lds[base + 25] ? lds[base + 24] : lds[base + 25];
        pooled[(size_t)b * 9216 + e] = m0 > m1 ? m0 : m1;
    }
}

// ---- fc1 MFMA: pooled[2048,9216]bf16 x wf1[128,9216]bf16^T, 4-way K-split ----
// grid (64,4): 32-row M tile, 2304 K slice; 4 waves each own 32 N-cols
__global__ __launch_bounds__(256) void fc1_mfma(
    const ushort* __restrict__ pooled, const ushort* __restrict__ wf1,
    float* __restrict__ part)
{
    int bx = blockIdx.x, by = blockIdx.y;
    int tid = threadIdx.x;
    int wid = tid >> 6, lane = tid & 63;
    int lo = lane & 15, hi = lane >> 4;
    int m0 = bx * 32;
    int kb = by * 2304;

    f32x4 acc[2][2];
#pragma unroll
    for (int mt = 0; mt < 2; ++mt)
#pragma unroll
        for (int j = 0; j < 2; ++j) acc[mt][j] = (f32x4)0.f;

    const ushort* arow0 = pooled + (size_t)(m0 + lo) * 9216 + kb + hi * 8;
    const ushort* arow1 = arow0 + 16 * 9216;
    const ushort* brow0 = wf1 + (size_t)(wid * 32 + lo) * 9216 + kb + hi * 8;
    const ushort* brow1 = brow0 + 16 * 9216;

    for (int kt = 0; kt < 72; ++kt) {
        short8 a0 = *(const short8*)(arow0 + kt * 32);
        short8 a1 = *(const short8*)(arow1 + kt * 32);
        short8 b0 = *(const short8*)(brow0 + kt * 32);
        short8 b1 = *(const short8*)(brow1 + kt * 32);
        acc[0][0] = __builtin_amdgcn_mfma_f32_16x16x32_bf16(a0, b0, acc[0][0], 0, 0, 0);
        acc[1][0] = __builtin_amdgcn_mfma_f32_16x16x32_bf16(a1, b0, acc[1][0], 0, 0, 0);
        acc[0][1] = __builtin_amdgcn_mfma_f32_16x16x32_bf16(a0, b1, acc[0][1], 0, 0, 0);
        acc[1][1] = __builtin_amdgcn_mfma_f32_16x16x32_bf16(a1, b1, acc[1][1], 0, 0, 0);
    }
    float* pp = part + (size_t)by * 262144;
#pragma unroll
    for (int mt = 0; mt < 2; ++mt)
#pragma unroll
        for (int j = 0; j < 2; ++j)
#pragma unroll
            for (int r = 0; r < 4; ++r)
                pp[(m0 + mt * 16 + hi * 4 + r) * 128 + wid * 32 + j * 16 + lo] = acc[mt][j][r];
}

__global__ __launch_bounds__(256) void fc1_reduce_kernel(
    const float* __restrict__ part, const float* __restrict__ bias,
    float* __restrict__ outp)
{
    int idx = blockIdx.x * 256 + threadIdx.x;   // < 262144
    float s = 0.f;
#pragma unroll
    for (int ks = 0; ks < 4; ++ks) s += part[ks * 262144 + idx];
    outp[idx] = fmaxf(s + bias[idx & 127], 0.f);
}

// ---- fc2 + sigmoid*2pi -> angles[2048,10] ----
__global__ __launch_bounds__(256) void fc2_kernel(
    const float* __restrict__ h, const float* __restrict__ w,
    const float* __restrict__ bias, float* __restrict__ ang)
{
    int idx = blockIdx.x * 256 + threadIdx.x;
    if (idx >= 20480) return;
    int b = idx / 10, n = idx % 10;
    const float* hp = h + b * 128;
    const float* wp = w + n * 128;
    float s = bias[n];
    for (int k = 0; k < 128; ++k) s = fmaf(hp[k], wp[k], s);
    ang[idx] = 6.28318530718f / (1.f + expf(-s));
}

// ---------------- quantum circuit + <Y_k> + log_softmax ----------------
__device__ __forceinline__ void apply_rot(float2* s, int p, float phi, float th,
                                          float om, int tid)
{
    float c, sn; sincosf(0.5f * th, &sn, &c);
    float A = 0.5f * (phi + om), Bv = 0.5f * (phi - om);
    float cA, sA; sincosf(A, &sA, &cA);
    float cB, sB; sincosf(Bv, &sB, &cB);
    float2 m00 = make_float2(cA * c, -sA * c);
    float2 m01 = make_float2(-cB * sn, -sB * sn);
    float2 m10 = make_float2(cB * sn, -sB * sn);
    float2 m11 = make_float2(cA * c, sA * c);
    for (int q = tid; q < 512; q += 256) {
        int i0 = ((q >> p) << (p + 1)) | (q & ((1 << p) - 1));
        int i1 = i0 | (1 << p);
        float2 aa = s[i0], bb = s[i1];
        s[i0] = make_float2(m00.x * aa.x - m00.y * aa.y + m01.x * bb.x - m01.y * bb.y,
                            m00.x * aa.y + m00.y * aa.x + m01.x * bb.y + m01.y * bb.x);
        s[i1] = make_float2(m10.x * aa.x - m10.y * aa.y + m11.x * bb.x - m11.y * bb.y,
                            m10.x * aa.y + m10.y * aa.x + m11.x * bb.y + m11.y * bb.x);
    }
}

__global__ __launch_bounds__(256) void quantum_kernel(
    const float* __restrict__ ang, const float* __restrict__ theta0,
    const float* __restrict__ theta_rz, const float* __restrict__ theta_ps,
    const float* __restrict__ rot_p, float* __restrict__ out)
{
    __shared__ float2 s[1024];
    __shared__ float red[40];
    int b = blockIdx.x;
    int tid = threadIdx.x;

    float a[10];
#pragma unroll
    for (int k = 0; k < 10; ++k) a[k] = ang[b * 10 + k];
    float th[10];
#pragma unroll
    for (int k = 0; k < 10; ++k) th[k] = theta0[k] + a[k];
    th[1] += a[1];
    th[5] -= 0.78539816339745f;   // RX(-pi/4) on wire 5

    float2 v[10][2];
#pragma unroll
    for (int k = 0; k < 10; ++k) {
        float c, sn; sincosf(0.5f * th[k], &sn, &c);
        v[k][0] = make_float2(c, 0.f);
        v[k][1] = make_float2(0.f, -sn);
    }
    { float c, sn; sincosf(0.5f * a[2], &sn, &c);
      float2 v0 = v[2][0], v1 = v[2][1];
      v[2][0] = make_float2(c * v0.x - sn * v1.x, c * v0.y - sn * v1.y);
      v[2][1] = make_float2(sn * v0.x + c * v1.x, sn * v0.y + c * v1.y); }
    { float c, sn; sincosf(0.5f * a[3], &sn, &c);
      v[3][0] = cmul(v[3][0], make_float2(c, -sn));
      v[3][1] = cmul(v[3][1], make_float2(c, sn)); }
    { float2 t = v[4][1]; v[4][1] = make_float2(-t.y, t.x); }
    { const float r = 0.70710678118655f;
      float2 t = v[5][1]; v[5][1] = make_float2(r * (t.x - t.y), r * (t.x + t.y)); }
    { float c, sn; sincosf(0.5f * theta_rz[0], &sn, &c);
      v[6][0] = cmul(v[6][0], make_float2(c, -sn));
      v[6][1] = cmul(v[6][1], make_float2(c, sn)); }
    { float2 p = v[7][0], q = v[7][1];
      v[7][0] = make_float2(0.5f * ((p.x - p.y) + (q.x + q.y)),
                            0.5f * ((p.x + p.y) + (q.y - q.x)));
      v[7][1] = make_float2(0.5f * ((p.x + p.y) + (q.x - q.y)),
                            0.5f * ((p.y - p.x) + (q.x + q.y))); }

    for (int i = tid; i < 1024; i += 256) {
        float2 c = v[0][(i >> 9) & 1];
#pragma unroll
        for (int k = 1; k < 10; ++k)
            c = cmul(c, v[k][(i >> (9 - k)) & 1]);
        s[i] = c;
    }
    __syncthreads();

    for (int i = tid; i < 1024; i += 256)
        if (((i >> 9) & 1) && ((i >> 4) & 1)) { s[i].x = -s[i].x; s[i].y = -s[i].y; }
    __syncthreads();
    { int j = tid;
      int i0 = 512 | ((j >> 4) << 5) | (j & 15);
      int i1 = i0 | 16;
      float2 t0 = s[i0], t1 = s[i1];
      s[i0] = t1; s[i1] = t0; }
    __syncthreads();
    { int j = tid;
      int i0 = 512 | ((j >> 4) << 5) | (j & 15);
      int i1 = i0 | 16;
      float2 t0 = s[i0], t1 = s[i1];
      s[i0] = make_float2(t1.y, -t1.x);
      s[i1] = make_float2(-t0.y, t0.x); }
    __syncthreads();
    { int j = tid;
      int i0 = (j & 1) | (((j >> 1) & 15) << 2) | (((j >> 5) & 7) << 7) | 64;
      int i1 = i0 | 2;
      float2 t0 = s[i0], t1 = s[i1];
      s[i0] = make_float2(t1.y, -t1.x);
      s[i1] = make_float2(-t0.y, t0.x); }
    __syncthreads();
    { int j = tid;
      int i0 = (j & 63) | 128 | (((j >> 6) & 3) << 8);
      int i1 = i0 ^ 0xC0;
      float2 t0 = s[i0], t1 = s[i1];
      s[i0] = t1; s[i1] = t0; }
    __syncthreads();
    if (tid < 128) {
      int j = tid;
      int i0 = (j & 7) | 16 | 32 | (((j >> 3) & 15) << 6);
      int i1 = i0 ^ 0x18;
      float2 t0 = s[i0], t1 = s[i1];
      s[i0] = t1; s[i1] = t0; }
    __syncthreads();
    if (tid < 128) {
      int j = tid;
      int i0 = (j & 1) | 2 | (((j >> 1) & 3) << 2) | 16 | (((j >> 3) & 15) << 5);
      int i1 = i0 | 512;
      float2 t0 = s[i0], t1 = s[i1];
      s[i0] = t1; s[i1] = t0; }
    __syncthreads();
    { float c1, s1; sincosf(theta_ps[0], &s1, &c1);
      float c2, s2; sincosf(a[7], &s2, &c2);
      float2 p1 = make_float2(c1, s1), p2 = make_float2(c2, s2);
      for (int i = tid; i < 1024; i += 256) {
          float2 t = s[i];
          if ((i >> 1) & 1) t = cmul(t, p1);
          if ((i >> 2) & 1) t = cmul(t, p2);
          s[i] = t;
      } }
    __syncthreads();
    apply_rot(s, 5, rot_p[0], rot_p[1], rot_p[2], tid);
    __syncthreads();
    apply_rot(s, 4, a[6], a[7], a[8], tid);
    __syncthreads();

    int wave = tid >> 6;
    for (int k = 0; k < 10; ++k) {
        int p = 9 - k;
        float part = 0.f;
        for (int q = tid; q < 512; q += 256) {
            int i0 = ((q >> p) << (p + 1)) | (q & ((1 << p) - 1));
            int i1 = i0 | (1 << p);
            float2 aa = s[i0], bb = s[i1];
            part += aa.x * bb.y - aa.y * bb.x;
        }
        part *= 2.f;
#pragma unroll
        for (int off = 32; off > 0; off >>= 1)
            part += __shfl_down(part, off, 64);
        if ((tid & 63) == 0) red[k * 4 + wave] = part;
    }
    __syncthreads();
    if (tid == 0) {
        float ev[10];
        float mx = -1e30f;
#pragma unroll
        for (int k = 0; k < 10; ++k) {
            ev[k] = red[k * 4] + red[k * 4 + 1] + red[k * 4 + 2] + red[k * 4 + 3];
            mx = fmaxf(mx, ev[k]);
        }
        float sum = 0.f;
#pragma unroll
        for (int k = 0; k < 10; ++k) sum += expf(ev[k] - mx);
        float lse = mx + logf(sum);
#pragma unroll
        for (int k = 0; k < 10; ++k) out[b * 10 + k] = ev[k] - lse;
    }
}

extern "C" void kernel_launch(void* const* d_in, const int* in_sizes, int n_in,
                              void* d_out, int out_size, void* d_ws, size_t ws_size,
                              hipStream_t stream)
{
    (void)in_sizes; (void)n_in; (void)out_size; (void)ws_size;
    const float* x    = (const float*)d_in[0];
    const float* c1w  = (const float*)d_in[1];
    const float* c1b  = (const float*)d_in[2];
    const float* c2w  = (const float*)d_in[3];
    const float* c2b  = (const float*)d_in[4];
    const float* f1w  = (const float*)d_in[5];
    const float* f1b  = (const float*)d_in[6];
    const float* f2w  = (const float*)d_in[7];
    const float* f2b  = (const float*)d_in[8];
    const float* th0  = (const float*)d_in[9];
    const float* trz  = (const float*)d_in[10];
    const float* tps  = (const float*)d_in[11];
    const float* rotp = (const float*)d_in[12];
    float* out = (float*)d_out;

    char* ws = (char*)d_ws;
    ushort* h1b    = (ushort*)(ws);                       // 88,604,672 B
    ushort* pooled = (ushort*)(ws + 88604672);            // 37,748,736 B
    ushort* wt2    = (ushort*)(ws + 126353408);           //     36,864 B
    ushort* wf1    = (ushort*)(ws + 126390272);           //  2,359,296 B
    float*  part   = (float*)(ws + 128749568);            //  4,194,304 B
    float*  fc1o   = (float*)(ws + 132943872);            //  1,048,576 B
    float*  ang    = (float*)(ws + 133992448);            //     81,920 B

    prep_kernel<<<4680, 256, 0, stream>>>(c2w, f1w, wt2, wf1);
    conv1_kernel<<<21632, 256, 0, stream>>>(x, c1w, c1b, h1b);
    conv2_mfma<<<2048, 384, 0, stream>>>(h1b, wt2, c2b, pooled);
    fc1_mfma<<<dim3(64, 4), 256, 0, stream>>>(pooled, wf1, part);
    fc1_reduce_kernel<<<1024, 256, 0, stream>>>(part, f1b, fc1o);
    fc2_kernel<<<80, 256, 0, stream>>>(fc1o, f2w, f2b, ang);
    quantum_kernel<<<2048, 256, 0, stream>>>(ang, th0, trz, tps, rotp, out);
}